// Round 3
// baseline (291.221 us; speedup 1.0000x reference)
//
#include <hip/hip_runtime.h>

// ---------------------------------------------------------------------------
// CrossAttention: B=8, T=S=1024, E=H=768, fp32 in/out, bf16 MFMA internally.
//
// Round 3: barrier-free wave-autonomous GEMM. Each wave computes a 64x64
// output tile from a wave-private 8KB LDS buffer; no __syncthreads in the
// K-loop. Per-wave s_waitcnt only; next tile's global_load_lds issued
// before the MFMA block so load latency overlaps compute within the wave.
// ---------------------------------------------------------------------------

typedef __bf16 bf16x8 __attribute__((ext_vector_type(8)));
typedef float  f32x4  __attribute__((ext_vector_type(4)));

__device__ __forceinline__ unsigned short f2bf(float f) {
    unsigned int u = __float_as_uint(f);
    u += 0x7fffu + ((u >> 16) & 1u);   // RNE; inputs are finite
    return (unsigned short)(u >> 16);
}

__device__ __forceinline__ void async_copy16(const void* g, void* s) {
    __builtin_amdgcn_global_load_lds(
        (const __attribute__((address_space(1))) void*)g,
        (__attribute__((address_space(3))) void*)s, 16, 0, 0);
}

// One wave computes C[row0:row0+64, col0:col0+64].
// Ag: A row row0 base, layout [*, K] bf16.  Bg: B^T row col0 base, [*, K].
// Exactly one of Cf/Cb non-null. transC: store C^T as [b][H][S] (vt).
__device__ __forceinline__ void wave_gemm(
    const unsigned short* __restrict__ Ag,
    const unsigned short* __restrict__ Bg,
    const int K,
    float* __restrict__ Cf, unsigned short* __restrict__ Cb,
    const long ldc, const int transC, const float* __restrict__ bias,
    const float scale, const long row0, const long col0,
    unsigned short* __restrict__ sA)     // wave-private 8KB (A 4KB | B 4KB)
{
    unsigned short* sB = sA + 2048;
    const int lane = threadIdx.x & 63;
    const int quad = lane >> 4;
    const int l16  = lane & 15;
    const int sw   = (quad ^ ((l16 >> 1) & 3)) * 8;   // swizzled read slot

    // staging source offsets (elements); slot c=h*64+lane holds source
    // k-chunk (c&3)^((r>>1)&3) of row r=c>>2 — matches read-side sw.
    long aoff[4];
#pragma unroll
    for (int h = 0; h < 4; ++h) {
        const int r  = h * 16 + (lane >> 2);
        const int jj = (lane & 3) ^ ((r >> 1) & 3);
        aoff[h] = (long)r * K + jj * 8;
    }

    f32x4 acc[4][4];
#pragma unroll
    for (int i = 0; i < 4; ++i)
#pragma unroll
        for (int j = 0; j < 4; ++j)
            acc[i][j] = f32x4{0.f, 0.f, 0.f, 0.f};

    const int nk = K >> 5;
    // prime tile 0
#pragma unroll
    for (int h = 0; h < 4; ++h) {
        async_copy16(Ag + aoff[h], &sA[(h * 64 + lane) * 8]);
        async_copy16(Bg + aoff[h], &sB[(h * 64 + lane) * 8]);
    }
    int k0 = 32;
    for (int t = 0; t < nk; ++t) {
        __builtin_amdgcn_s_waitcnt(0x0F70);   // vmcnt(0): tile t landed in LDS
        bf16x8 af[4], bf[4];
#pragma unroll
        for (int i = 0; i < 4; ++i) {
            af[i] = *(const bf16x8*)&sA[(i * 16 + l16) * 32 + sw];
            bf[i] = *(const bf16x8*)&sB[(i * 16 + l16) * 32 + sw];
        }
        __builtin_amdgcn_s_waitcnt(0xC07F);   // lgkmcnt(0): frags in registers
        if (t + 1 < nk) {                     // prefetch tile t+1 (LDS now dead)
#pragma unroll
            for (int h = 0; h < 4; ++h) {
                async_copy16(Ag + k0 + aoff[h], &sA[(h * 64 + lane) * 8]);
                async_copy16(Bg + k0 + aoff[h], &sB[(h * 64 + lane) * 8]);
            }
            k0 += 32;
        }
#pragma unroll
        for (int i = 0; i < 4; ++i)
#pragma unroll
            for (int j = 0; j < 4; ++j)
                acc[i][j] = __builtin_amdgcn_mfma_f32_16x16x32_bf16(
                    af[i], bf[j], acc[i][j], 0, 0, 0);
    }

    // epilogue: C/D layout col=lane&15, row=quad*4+reg  [m89/m91 verified]
#pragma unroll
    for (int i = 0; i < 4; ++i) {
#pragma unroll
        for (int j = 0; j < 4; ++j) {
            const long r0 = row0 + i * 16 + quad * 4;
            const long c  = col0 + j * 16 + l16;
            const float bb = bias ? bias[c] : 0.0f;
#pragma unroll
            for (int r = 0; r < 4; ++r) {
                const float v = acc[i][j][r] * scale + bb;
                const long rr = r0 + r;
                if (Cb) {
                    if (transC) {
                        Cb[((rr >> 10) * 768 + c) * 1024 + (rr & 1023)] = f2bf(v);
                    } else {
                        Cb[rr * ldc + c] = f2bf(v);
                    }
                } else {
                    Cf[rr * ldc + c] = v;
                }
            }
        }
    }
}

// ---------------------------------------------------------------------------

__global__ __launch_bounds__(256, 3) void proj_qkv(
    const unsigned short* __restrict__ xb, const unsigned short* __restrict__ eb,
    const unsigned short* __restrict__ wqt, const unsigned short* __restrict__ wkt,
    const unsigned short* __restrict__ wvt,
    const float* __restrict__ bq, const float* __restrict__ bk,
    const float* __restrict__ bv,
    unsigned short* __restrict__ q, unsigned short* __restrict__ k,
    unsigned short* __restrict__ vt)
{
    __shared__ __align__(16) unsigned short smem[4][4096];
    const int wave = threadIdx.x >> 6;
    const int t    = blockIdx.x * 4 + wave;   // 0..1535
    const int row  = t / 12, col = t % 12;

    const unsigned short *A, *Bt; const float* bias; unsigned short* C;
    int trans = 0;
    switch (blockIdx.y) {
        case 0:  A = xb; Bt = wqt; bias = bq; C = q;  break;
        case 1:  A = eb; Bt = wkt; bias = bk; C = k;  break;
        default: A = eb; Bt = wvt; bias = bv; C = vt; trans = 1; break;
    }
    wave_gemm(A + (long)row * 64 * 768, Bt + (long)col * 64 * 768, 768,
              nullptr, C, 768, trans, bias, 1.0f,
              (long)row * 64, (long)col * 64, smem[wave]);
}

__global__ __launch_bounds__(256, 3) void scores_gemm(
    const unsigned short* __restrict__ q, const unsigned short* __restrict__ k,
    float* __restrict__ sc, float scale)
{
    __shared__ __align__(16) unsigned short smem[4][4096];
    const int wave = threadIdx.x >> 6;
    const int t    = blockIdx.x * 4 + wave;   // 0..2047
    const int row  = t / 16, col = t % 16;
    const int b    = row >> 4;
    wave_gemm(q + (long)row * 64 * 768, k + (long)b * 786432 + (long)col * 64 * 768,
              768, sc, nullptr, 1024, 0, nullptr, scale,
              (long)row * 64, (long)col * 64, smem[wave]);
}

__global__ __launch_bounds__(256, 3) void pv_gemm(
    const unsigned short* __restrict__ p, const unsigned short* __restrict__ vt,
    unsigned short* __restrict__ ao)
{
    __shared__ __align__(16) unsigned short smem[4][4096];
    const int wave = threadIdx.x >> 6;
    const int t    = blockIdx.x * 4 + wave;   // 0..1535
    const int row  = t / 12, col = t % 12;
    const int b    = row >> 4;
    wave_gemm(p + (long)row * 64 * 1024, vt + (long)b * 786432 + (long)col * 64 * 1024,
              1024, nullptr, ao, 768, 0, nullptr, 1.0f,
              (long)row * 64, (long)col * 64, smem[wave]);
}

__global__ __launch_bounds__(256, 3) void outproj_gemm(
    const unsigned short* __restrict__ ao, const unsigned short* __restrict__ wpt,
    float* __restrict__ out, const float* __restrict__ bp)
{
    __shared__ __align__(16) unsigned short smem[4][4096];
    const int wave = threadIdx.x >> 6;
    const int t    = blockIdx.x * 4 + wave;   // 0..1535
    const int row  = t / 12, col = t % 12;
    wave_gemm(ao + (long)row * 64 * 768, wpt + (long)col * 64 * 768, 768,
              out, nullptr, 768, 0, bp, 1.0f,
              (long)row * 64, (long)col * 64, smem[wave]);
}

// ---------------------------------------------------------------------------

__global__ __launch_bounds__(256) void convert_inputs(
    const float* __restrict__ x, const float* __restrict__ enc,
    unsigned short* __restrict__ xb, unsigned short* __restrict__ eb, int nper)
{
    const int i = blockIdx.x * 256 + threadIdx.x;   // float4 index
    const bool second = (i >= nper);
    const int idx = second ? i - nper : i;
    const float4 v = second ? ((const float4*)enc)[idx] : ((const float4*)x)[idx];
    ushort4 o;
    o.x = f2bf(v.x); o.y = f2bf(v.y); o.z = f2bf(v.z); o.w = f2bf(v.w);
    if (second) ((ushort4*)eb)[idx] = o;
    else        ((ushort4*)xb)[idx] = o;
}

__global__ __launch_bounds__(256) void transpose_w(
    const float* __restrict__ w0, const float* __restrict__ w1,
    const float* __restrict__ w2, const float* __restrict__ w3,
    unsigned short* __restrict__ o0, unsigned short* __restrict__ o1,
    unsigned short* __restrict__ o2, unsigned short* __restrict__ o3)
{
    const float* w; unsigned short* o;
    switch (blockIdx.z) {
        case 0:  w = w0; o = o0; break;
        case 1:  w = w1; o = o1; break;
        case 2:  w = w2; o = o2; break;
        default: w = w3; o = o3; break;
    }
    __shared__ float t[32][33];
    const int tx = threadIdx.x & 31;
    const int ty = threadIdx.x >> 5;          // 0..7
    const int k0 = blockIdx.x * 32;
    const int n0 = blockIdx.y * 32;
#pragma unroll
    for (int i = 0; i < 4; ++i)
        t[ty + i * 8][tx] = w[(long)(k0 + ty + i * 8) * 768 + n0 + tx];
    __syncthreads();
#pragma unroll
    for (int i = 0; i < 4; ++i)
        o[(long)(n0 + ty + i * 8) * 768 + k0 + tx] = f2bf(t[tx][ty + i * 8]);
}

__global__ __launch_bounds__(256) void softmax_rows(
    const float* __restrict__ S, unsigned short* __restrict__ P)
{
    const long row = blockIdx.x;                 // 8192 rows of 1024
    const float* s = S + row * 1024;
    unsigned short* p = P + row * 1024;
    const int tid  = threadIdx.x;
    const int lane = tid & 63;
    const int wave = tid >> 6;

    float4 v = ((const float4*)s)[tid];
    float m = fmaxf(fmaxf(v.x, v.y), fmaxf(v.z, v.w));
#pragma unroll
    for (int off = 32; off > 0; off >>= 1)
        m = fmaxf(m, __shfl_xor(m, off));
    __shared__ float redm[4], reds[4];
    if (lane == 0) redm[wave] = m;
    __syncthreads();
    m = fmaxf(fmaxf(redm[0], redm[1]), fmaxf(redm[2], redm[3]));

    const float e0 = __expf(v.x - m), e1 = __expf(v.y - m);
    const float e2 = __expf(v.z - m), e3 = __expf(v.w - m);
    float sum = e0 + e1 + e2 + e3;
#pragma unroll
    for (int off = 32; off > 0; off >>= 1)
        sum += __shfl_xor(sum, off);
    if (lane == 0) reds[wave] = sum;
    __syncthreads();
    const float inv = 1.0f / (reds[0] + reds[1] + reds[2] + reds[3]);

    ushort4 o;
    o.x = f2bf(e0 * inv); o.y = f2bf(e1 * inv);
    o.z = f2bf(e2 * inv); o.w = f2bf(e3 * inv);
    ((ushort4*)p)[tid] = o;
}

// ---------------------------------------------------------------------------

extern "C" void kernel_launch(void* const* d_in, const int* in_sizes, int n_in,
                              void* d_out, int out_size, void* d_ws, size_t ws_size,
                              hipStream_t stream) {
    const float* x   = (const float*)d_in[0];
    const float* enc = (const float*)d_in[1];
    const float* Wq  = (const float*)d_in[2];
    const float* bq  = (const float*)d_in[3];
    const float* Wk  = (const float*)d_in[4];
    const float* bk  = (const float*)d_in[5];
    const float* Wv  = (const float*)d_in[6];
    const float* bv  = (const float*)d_in[7];
    const float* Wp  = (const float*)d_in[8];
    const float* bp  = (const float*)d_in[9];
    float* out = (float*)d_out;

    // workspace layout (bytes); peak need ~101.2 MB
    char* ws = (char*)d_ws;
    unsigned short* xb  = (unsigned short*)(ws + 0);         // 12582912
    unsigned short* eb  = (unsigned short*)(ws + 12582912);  // 12582912
    unsigned short* q   = (unsigned short*)(ws + 25165824);  // 12582912
    unsigned short* k   = (unsigned short*)(ws + 37748736);  // 12582912
    unsigned short* vt  = (unsigned short*)(ws + 50331648);  // 12582912 [B][H][S]
    unsigned short* wqt = (unsigned short*)(ws + 62914560);  // 1179648
    unsigned short* wkt = (unsigned short*)(ws + 64094208);  // 1179648
    unsigned short* wvt = (unsigned short*)(ws + 65273856);  // 1179648
    unsigned short* wpt = (unsigned short*)(ws + 66453504);  // 1179648
    float*          sc  = (float*)(ws + 67633152);           // 33554432 fp32 scores
    unsigned short* p   = (unsigned short*)(ws + 0);         // 16777216, overlays xb/eb (dead)
    unsigned short* ao  = (unsigned short*)(ws + 67633152);  // 12582912, overlays sc (dead)

    const float scale = 0.03608439182435161f;  // 1/sqrt(768)

    // 1. fp32 -> bf16 for x and encoder_out
    convert_inputs<<<12288, 256, 0, stream>>>(x, enc, xb, eb, 1572864);

    // 2. W^T bf16 for all four weights
    transpose_w<<<dim3(24, 24, 4), 256, 0, stream>>>(Wq, Wk, Wv, Wp, wqt, wkt, wvt, wpt);

    // 3. q/k/v projections: 1536 wave-tiles per z
    proj_qkv<<<dim3(384, 3), 256, 0, stream>>>(xb, eb, wqt, wkt, wvt, bq, bk, bv, q, k, vt);

    // 4. scores = q k^T * scale (fp32): 2048 wave-tiles
    scores_gemm<<<512, 256, 0, stream>>>(q, k, sc, scale);

    // 5. softmax rows -> bf16 P
    softmax_rows<<<8192, 256, 0, stream>>>(sc, p);

    // 6. ao = P @ V: 1536 wave-tiles
    pv_gemm<<<384, 256, 0, stream>>>(p, vt, ao);

    // 7. out = ao @ Wp + bp: 1536 wave-tiles
    outproj_gemm<<<384, 256, 0, stream>>>(ao, wpt, out, bp);
}